// Round 1
// baseline (213.465 us; speedup 1.0000x reference)
//
#include <hip/hip_runtime.h>
#include <hip/hip_bf16.h>

// TripletLoss: fused E·E^T + masked row min/max reduction.
// B=8192, D=256. Never materialize the 8192^2 sim matrix.
//
// dist = sqrt(2-2*sim) is monotone decreasing in sim, so:
//   dist_ap = dist(min sim over positives), dist_an = dist(max sim over negatives).
// Per-row state stored as int bits of (sim+2) (positive floats -> int order == float order).

#define BDIM 8192
#define DDIM 256

typedef short bf16x8 __attribute__((ext_vector_type(8)));
typedef float f32x4  __attribute__((ext_vector_type(4)));
typedef unsigned short u16;

static __device__ __forceinline__ bf16x8 ld_frag(const u16* p) {
    return *reinterpret_cast<const bf16x8*>(p);  // 16B aligned by construction
}

static __device__ __forceinline__ u16 f2bf(float f) {
    union { float f; unsigned int u; } x; x.f = f;
    unsigned int u = x.u;
    unsigned int r = u + 0x7fffu + ((u >> 16) & 1u);  // RNE
    return (u16)(r >> 16);
}

// ---- kernel 1: fp32 -> bf16 convert (vectorized 4/thread) ----
__global__ __launch_bounds__(256) void cvt_kernel(const float* __restrict__ in,
                                                  u16* __restrict__ out) {
    int i = blockIdx.x * 256 + threadIdx.x;          // 524288 threads, 4 elems each
    const float4 v = reinterpret_cast<const float4*>(in)[i];
    ushort4 o;
    o.x = f2bf(v.x); o.y = f2bf(v.y); o.z = f2bf(v.z); o.w = f2bf(v.w);
    reinterpret_cast<ushort4*>(out)[i] = o;
}

// ---- kernel 2: init reduction arrays ----
__global__ __launch_bounds__(256) void init_kernel(int* __restrict__ minpos,
                                                   int* __restrict__ maxneg) {
    int i = blockIdx.x * 256 + threadIdx.x;          // 8192 threads
    minpos[i] = 0x7f800000;                          // +inf  (min over positives of sim+2)
    maxneg[i] = 0;                                   // 0.0f  (max over negatives of sim+2; real vals >= ~0.98)
}

// ---- kernel 3: fused GEMM + masked row min/max ----
// block = 256 threads = 4 waves. Wave w owns rows [mblk + w*32, +32) (2 m-subtiles).
// Block sweeps 512 columns (blockIdx.y chunk), 64 at a time (4 n-subtiles).
// A fragments (2 m-subtiles x 8 k-steps) preloaded into registers.
__global__ __launch_bounds__(256) void triplet_main(const u16* __restrict__ Ebf,
                                                    const int* __restrict__ labels,
                                                    int* __restrict__ minpos,
                                                    int* __restrict__ maxneg) {
    const int tid  = threadIdx.x;
    const int w    = tid >> 6;
    const int l    = tid & 63;
    const int quad = l >> 4;
    const int r16  = l & 15;

    const int mblk  = blockIdx.x * 128 + w * 32;     // wave's first row
    const int nbase = blockIdx.y * 512;

    // Preload A fragments: a[ms][k] covers rows [mblk+ms*16, +16), k = [k*32, +32)
    bf16x8 a[2][8];
#pragma unroll
    for (int ms = 0; ms < 2; ++ms) {
        const u16* ap = Ebf + (size_t)(mblk + ms * 16 + r16) * DDIM + quad * 8;
#pragma unroll
        for (int k = 0; k < 8; ++k) a[ms][k] = ld_frag(ap + k * 32);
    }

    int lab_row[2][4];
#pragma unroll
    for (int ms = 0; ms < 2; ++ms)
#pragma unroll
        for (int r = 0; r < 4; ++r)
            lab_row[ms][r] = labels[mblk + ms * 16 + quad * 4 + r];

    float minp[2][4], maxn[2][4];
#pragma unroll
    for (int ms = 0; ms < 2; ++ms)
#pragma unroll
        for (int r = 0; r < 4; ++r) { minp[ms][r] = __builtin_inff(); maxn[ms][r] = 0.0f; }

    for (int nn = 0; nn < 8; ++nn) {                 // 8 x 64 = 512 columns
        const int n0 = nbase + nn * 64;
        f32x4 acc[2][4];
#pragma unroll
        for (int ms = 0; ms < 2; ++ms)
#pragma unroll
            for (int nt = 0; nt < 4; ++nt)
                acc[ms][nt] = (f32x4){0.f, 0.f, 0.f, 0.f};

        const u16* bp0 = Ebf + (size_t)(n0 + r16) * DDIM + quad * 8;
#pragma unroll
        for (int k = 0; k < 8; ++k) {
            bf16x8 b[4];
#pragma unroll
            for (int nt = 0; nt < 4; ++nt)
                b[nt] = ld_frag(bp0 + (size_t)nt * 16 * DDIM + k * 32);
#pragma unroll
            for (int ms = 0; ms < 2; ++ms)
#pragma unroll
                for (int nt = 0; nt < 4; ++nt)
                    acc[ms][nt] = __builtin_amdgcn_mfma_f32_16x16x32_bf16(
                        a[ms][k], b[nt], acc[ms][nt], 0, 0, 0);
        }

        // masked fold into per-lane running min/max
#pragma unroll
        for (int nt = 0; nt < 4; ++nt) {
            const int colg  = n0 + nt * 16 + r16;
            const int lab_c = labels[colg];
#pragma unroll
            for (int ms = 0; ms < 2; ++ms) {
#pragma unroll
                for (int r = 0; r < 4; ++r) {
                    const int rowg = mblk + ms * 16 + quad * 4 + r;
                    const float sp2 = acc[ms][nt][r] + 2.0f;
                    if (colg != rowg) {
                        if (lab_c == lab_row[ms][r]) minp[ms][r] = fminf(minp[ms][r], sp2);
                        else                         maxn[ms][r] = fmaxf(maxn[ms][r], sp2);
                    }
                }
            }
        }
    }

    // reduce across the 16 lanes sharing a quad (same rows, different columns)
#pragma unroll
    for (int mask = 1; mask <= 8; mask <<= 1) {
#pragma unroll
        for (int ms = 0; ms < 2; ++ms)
#pragma unroll
            for (int r = 0; r < 4; ++r) {
                minp[ms][r] = fminf(minp[ms][r], __shfl_xor(minp[ms][r], mask, 64));
                maxn[ms][r] = fmaxf(maxn[ms][r], __shfl_xor(maxn[ms][r], mask, 64));
            }
    }
    if (r16 == 0) {
#pragma unroll
        for (int ms = 0; ms < 2; ++ms)
#pragma unroll
            for (int r = 0; r < 4; ++r) {
                const int rowg = mblk + ms * 16 + quad * 4 + r;
                atomicMin(minpos + rowg, __float_as_int(minp[ms][r]));
                atomicMax(maxneg + rowg, __float_as_int(maxn[ms][r]));
            }
    }
}

// ---- kernel 4: finalize (single block) ----
__global__ __launch_bounds__(256) void finalize_kernel(const int* __restrict__ minpos,
                                                       const int* __restrict__ maxneg,
                                                       float* __restrict__ out) {
    __shared__ float ssum[4], scnt[4];
    float sum = 0.f, cnt = 0.f;
    for (int i = threadIdx.x; i < BDIM; i += 256) {
        const float mp = __int_as_float(minpos[i]);  // min (sim+2) over positives; +inf if none
        const float mn = __int_as_float(maxneg[i]);  // max (sim+2) over negatives; 0 if none
        if (mp < 1e30f && mn > 0.5f) {
            const float s_ap = mp - 2.0f;
            const float s_an = mn - 2.0f;
            const float dap = sqrtf(fmaxf(2.0f - 2.0f * s_ap, 0.0f) + 1e-12f);
            const float dan = sqrtf(fmaxf(2.0f - 2.0f * s_an, 0.0f) + 1e-12f);
            sum += fmaxf(dap - dan + 0.3f, 0.0f);
            cnt += 1.0f;
        }
    }
#pragma unroll
    for (int off = 32; off > 0; off >>= 1) {
        sum += __shfl_down(sum, off, 64);
        cnt += __shfl_down(cnt, off, 64);
    }
    const int wid = threadIdx.x >> 6;
    if ((threadIdx.x & 63) == 0) { ssum[wid] = sum; scnt[wid] = cnt; }
    __syncthreads();
    if (threadIdx.x == 0) {
        const float S = ssum[0] + ssum[1] + ssum[2] + ssum[3];
        const float C = scnt[0] + scnt[1] + scnt[2] + scnt[3];
        out[0] = (C > 0.f) ? (S / C) : 0.f;
    }
}

extern "C" void kernel_launch(void* const* d_in, const int* in_sizes, int n_in,
                              void* d_out, int out_size, void* d_ws, size_t ws_size,
                              hipStream_t stream) {
    const float* emb    = (const float*)d_in[0];
    const int*   labels = (const int*)d_in[1];
    float*       out    = (float*)d_out;

    u16* Ebf    = (u16*)d_ws;                                  // 8192*256*2 = 4 MB
    int* minpos = (int*)((char*)d_ws + (size_t)BDIM * DDIM * 2);
    int* maxneg = minpos + BDIM;

    cvt_kernel<<<dim3((BDIM * DDIM / 4) / 256), dim3(256), 0, stream>>>(emb, Ebf);
    init_kernel<<<dim3(BDIM / 256), dim3(256), 0, stream>>>(minpos, maxneg);
    triplet_main<<<dim3(BDIM / 128, BDIM / 512), dim3(256), 0, stream>>>(Ebf, labels, minpos, maxneg);
    finalize_kernel<<<dim3(1), dim3(256), 0, stream>>>(minpos, maxneg, out);
}

// Round 2
// 117.835 us; speedup vs baseline: 1.8116x; 1.8116x over previous
//
#include <hip/hip_runtime.h>
#include <hip/hip_bf16.h>

// TripletLoss: fused E·E^T + masked row min/max reduction. B=8192, D=256.
// dist = sqrt(2-2*sim) monotone decreasing in sim =>
//   dist_ap = dist(min sim over positives), dist_an = dist(max sim over negatives).
// Row state stored as int bits of (sim+2) (positive floats: int order == float order).
//
// R2: B-tiles staged via global_load_lds (width 16, coalesced) into LDS,
// double-buffered, XOR-swizzled on the GLOBAL source address (global_load_lds
// LDS dest is linear lane*16 and can't be padded). A register-resident.

#define BDIM 8192
#define DDIM 256

typedef short bf16x8 __attribute__((ext_vector_type(8)));
typedef float f32x4  __attribute__((ext_vector_type(4)));
typedef unsigned short u16;

static __device__ __forceinline__ bf16x8 ld_frag(const u16* p) {
    return *reinterpret_cast<const bf16x8*>(p);
}

static __device__ __forceinline__ u16 f2bf(float f) {
    union { float f; unsigned int u; } x; x.f = f;
    unsigned int u = x.u;
    unsigned int r = u + 0x7fffu + ((u >> 16) & 1u);  // RNE
    return (u16)(r >> 16);
}

static __device__ __forceinline__ void gload_lds16(const u16* g, u16* l) {
    __builtin_amdgcn_global_load_lds(
        (const __attribute__((address_space(1))) unsigned int*)g,
        (__attribute__((address_space(3))) unsigned int*)l, 16, 0, 0);
}

// ---- kernel 1: fp32 -> bf16 convert + init reduction arrays ----
__global__ __launch_bounds__(256) void cvt_init_kernel(const float* __restrict__ in,
                                                       u16* __restrict__ out,
                                                       int* __restrict__ minpos,
                                                       int* __restrict__ maxneg) {
    int i = blockIdx.x * 256 + threadIdx.x;          // 524288 threads, 4 elems each
    const float4 v = reinterpret_cast<const float4*>(in)[i];
    ushort4 o;
    o.x = f2bf(v.x); o.y = f2bf(v.y); o.z = f2bf(v.z); o.w = f2bf(v.w);
    reinterpret_cast<ushort4*>(out)[i] = o;
    if (i < BDIM) {
        minpos[i] = 0x7f800000;                      // +inf (min over positives of sim+2)
        maxneg[i] = 0;                               // 0.0f (max over negatives of sim+2)
    }
}

// ---- kernel 2: fused GEMM + masked row min/max ----
// block = 256 threads = 4 waves. Wave w owns rows [bx*128 + w*32, +32).
// Block sweeps 1024 cols (by chunk), 64 at a time, B-tile (64x256 bf16 = 32KB)
// staged in LDS, double buffered. Swizzle: chunk c of row r at position c^(r&7).
__global__ __launch_bounds__(256, 2) void triplet_main(const u16* __restrict__ Ebf,
                                                       const int* __restrict__ labels,
                                                       int* __restrict__ minpos,
                                                       int* __restrict__ maxneg) {
    __shared__ __align__(16) u16 smem[2][64 * DDIM];  // 2 x 32 KB

    const int tid  = threadIdx.x;
    const int w    = tid >> 6;
    const int l    = tid & 63;
    const int quad = l >> 4;
    const int r16  = l & 15;

    const int mblk  = blockIdx.x * 128 + w * 32;
    const int nbase = blockIdx.y * 1024;

    // Preload A fragments: a[ms][k] covers rows [mblk+ms*16,+16), k-chunk [k*32,+32)
    bf16x8 a[2][8];
#pragma unroll
    for (int ms = 0; ms < 2; ++ms) {
        const u16* ap = Ebf + (size_t)(mblk + ms * 16 + r16) * DDIM + quad * 8;
#pragma unroll
        for (int k = 0; k < 8; ++k) a[ms][k] = ld_frag(ap + k * 32);
    }

    int lab_row[2][4];
#pragma unroll
    for (int ms = 0; ms < 2; ++ms)
#pragma unroll
        for (int r = 0; r < 4; ++r)
            lab_row[ms][r] = labels[mblk + ms * 16 + quad * 4 + r];

    float minp[2][4], maxn[2][4];
#pragma unroll
    for (int ms = 0; ms < 2; ++ms)
#pragma unroll
        for (int r = 0; r < 4; ++r) { minp[ms][r] = __builtin_inff(); maxn[ms][r] = 0.0f; }

    // swizzled-read lane constants
    const int qs  = quad ^ (r16 & 3);        // low-2-bit chunk index after swizzle
    const int s4  = (r16 >> 2) & 1;          // bit-2 of swizzle

    // stage first tile into buf 0
    {
        const int n0 = nbase;
#pragma unroll
        for (int it = 0; it < 8; ++it) {
            const int q = it * 256 + tid;            // block-linear 16B chunk
            const int r = q >> 5;
            const int c = (q & 31) ^ (r & 7);
            gload_lds16(Ebf + ((size_t)(n0 + r) << 8) + c * 8,
                        &smem[0][0] + it * 2048 + w * 512);
        }
    }

    for (int nn = 0; nn < 16; ++nn) {
        const int cur = nn & 1;
        const int n0  = nbase + nn * 64;

        __syncthreads();   // staging of smem[cur] complete; smem[!cur] free to overwrite

        if (nn + 1 < 16) { // prefetch next tile into the other buffer
            const int n1 = n0 + 64;
#pragma unroll
            for (int it = 0; it < 8; ++it) {
                const int q = it * 256 + tid;
                const int r = q >> 5;
                const int c = (q & 31) ^ (r & 7);
                gload_lds16(Ebf + ((size_t)(n1 + r) << 8) + c * 8,
                            &smem[cur ^ 1][0] + it * 2048 + w * 512);
            }
        }

        f32x4 acc[2][4];
#pragma unroll
        for (int ms = 0; ms < 2; ++ms)
#pragma unroll
            for (int nt = 0; nt < 4; ++nt)
                acc[ms][nt] = (f32x4){0.f, 0.f, 0.f, 0.f};

        const u16* bb = &smem[cur][0];
        const u16* bnt[4];
#pragma unroll
        for (int nt = 0; nt < 4; ++nt)
            bnt[nt] = bb + (nt * 16 + r16) * DDIM + qs * 8;

#pragma unroll
        for (int k = 0; k < 8; ++k) {
            const int koff = ((k ^ s4) << 5);        // element offset of swizzled k-chunk
            bf16x8 b[4];
#pragma unroll
            for (int nt = 0; nt < 4; ++nt) b[nt] = ld_frag(bnt[nt] + koff);
#pragma unroll
            for (int ms = 0; ms < 2; ++ms)
#pragma unroll
                for (int nt = 0; nt < 4; ++nt)
                    acc[ms][nt] = __builtin_amdgcn_mfma_f32_16x16x32_bf16(
                        a[ms][k], b[nt], acc[ms][nt], 0, 0, 0);
        }

        // masked fold into per-lane running min/max
        int lab_c[4];
#pragma unroll
        for (int nt = 0; nt < 4; ++nt) lab_c[nt] = labels[n0 + nt * 16 + r16];
#pragma unroll
        for (int nt = 0; nt < 4; ++nt) {
            const int colg = n0 + nt * 16 + r16;
#pragma unroll
            for (int ms = 0; ms < 2; ++ms) {
#pragma unroll
                for (int r = 0; r < 4; ++r) {
                    const int rowg = mblk + ms * 16 + quad * 4 + r;
                    const float sp2 = acc[ms][nt][r] + 2.0f;
                    if (colg != rowg) {
                        if (lab_c[nt] == lab_row[ms][r]) minp[ms][r] = fminf(minp[ms][r], sp2);
                        else                             maxn[ms][r] = fmaxf(maxn[ms][r], sp2);
                    }
                }
            }
        }
    }

    // reduce across the 16 lanes sharing a quad (same rows, different cols)
#pragma unroll
    for (int mask = 1; mask <= 8; mask <<= 1) {
#pragma unroll
        for (int ms = 0; ms < 2; ++ms)
#pragma unroll
            for (int r = 0; r < 4; ++r) {
                minp[ms][r] = fminf(minp[ms][r], __shfl_xor(minp[ms][r], mask, 64));
                maxn[ms][r] = fmaxf(maxn[ms][r], __shfl_xor(maxn[ms][r], mask, 64));
            }
    }
    if (r16 == 0) {
#pragma unroll
        for (int ms = 0; ms < 2; ++ms)
#pragma unroll
            for (int r = 0; r < 4; ++r) {
                const int rowg = mblk + ms * 16 + quad * 4 + r;
                atomicMin(minpos + rowg, __float_as_int(minp[ms][r]));
                atomicMax(maxneg + rowg, __float_as_int(maxn[ms][r]));
            }
    }
}

// ---- kernel 3: finalize (single block) ----
__global__ __launch_bounds__(256) void finalize_kernel(const int* __restrict__ minpos,
                                                       const int* __restrict__ maxneg,
                                                       float* __restrict__ out) {
    __shared__ float ssum[4], scnt[4];
    float sum = 0.f, cnt = 0.f;
    for (int i = threadIdx.x; i < BDIM; i += 256) {
        const float mp = __int_as_float(minpos[i]);
        const float mn = __int_as_float(maxneg[i]);
        if (mp < 1e30f && mn > 0.5f) {
            const float s_ap = mp - 2.0f;
            const float s_an = mn - 2.0f;
            const float dap = sqrtf(fmaxf(2.0f - 2.0f * s_ap, 0.0f) + 1e-12f);
            const float dan = sqrtf(fmaxf(2.0f - 2.0f * s_an, 0.0f) + 1e-12f);
            sum += fmaxf(dap - dan + 0.3f, 0.0f);
            cnt += 1.0f;
        }
    }
#pragma unroll
    for (int off = 32; off > 0; off >>= 1) {
        sum += __shfl_down(sum, off, 64);
        cnt += __shfl_down(cnt, off, 64);
    }
    const int wid = threadIdx.x >> 6;
    if ((threadIdx.x & 63) == 0) { ssum[wid] = sum; scnt[wid] = cnt; }
    __syncthreads();
    if (threadIdx.x == 0) {
        const float S = ssum[0] + ssum[1] + ssum[2] + ssum[3];
        const float C = scnt[0] + scnt[1] + scnt[2] + scnt[3];
        out[0] = (C > 0.f) ? (S / C) : 0.f;
    }
}

extern "C" void kernel_launch(void* const* d_in, const int* in_sizes, int n_in,
                              void* d_out, int out_size, void* d_ws, size_t ws_size,
                              hipStream_t stream) {
    const float* emb    = (const float*)d_in[0];
    const int*   labels = (const int*)d_in[1];
    float*       out    = (float*)d_out;

    u16* Ebf    = (u16*)d_ws;                                  // 4 MB
    int* minpos = (int*)((char*)d_ws + (size_t)BDIM * DDIM * 2);
    int* maxneg = minpos + BDIM;

    cvt_init_kernel<<<dim3((BDIM * DDIM / 4) / 256), dim3(256), 0, stream>>>(emb, Ebf, minpos, maxneg);
    triplet_main<<<dim3(BDIM / 128, BDIM / 1024), dim3(256), 0, stream>>>(Ebf, labels, minpos, maxneg);
    finalize_kernel<<<dim3(1), dim3(256), 0, stream>>>(minpos, maxneg, out);
}

// Round 4
// 105.223 us; speedup vs baseline: 2.0287x; 1.1199x over previous
//
#include <hip/hip_runtime.h>
#include <hip/hip_bf16.h>

// TripletLoss: fused E·E^T + masked row min/max reduction. B=8192, D=256.
// dist = sqrt(2-2*sim) monotone decreasing in sim =>
//   dist_ap = dist(min sim over positives), dist_an = dist(max sim over negatives).
//
// R4: R3 structure (ms=4: wave owns 64 rows, a[4][8] register-resident, each LDS
// B-fragment feeds 4 MFMAs; nt=2: 32-col B-tiles, 16KB, double-buffered) with the
// finalize constant fixed: stored value is sim+2, so 2-2*sim = 6-2*(sim+2).

#define BDIM 8192
#define DDIM 256

typedef short bf16x8 __attribute__((ext_vector_type(8)));
typedef float f32x4  __attribute__((ext_vector_type(4)));
typedef unsigned short u16;

static __device__ __forceinline__ bf16x8 ld_frag(const u16* p) {
    return *reinterpret_cast<const bf16x8*>(p);
}

static __device__ __forceinline__ u16 f2bf(float f) {
    union { float f; unsigned int u; } x; x.f = f;
    unsigned int u = x.u;
    unsigned int r = u + 0x7fffu + ((u >> 16) & 1u);  // RNE
    return (u16)(r >> 16);
}

static __device__ __forceinline__ void gload_lds16(const u16* g, u16* l) {
    __builtin_amdgcn_global_load_lds(
        (const __attribute__((address_space(1))) unsigned int*)g,
        (__attribute__((address_space(3))) unsigned int*)l, 16, 0, 0);
}

// ---- kernel 1: fp32 -> bf16 convert + init reduction arrays ----
__global__ __launch_bounds__(256) void cvt_init_kernel(const float* __restrict__ in,
                                                       u16* __restrict__ out,
                                                       int* __restrict__ minpos,
                                                       int* __restrict__ maxneg) {
    int i = blockIdx.x * 256 + threadIdx.x;          // 524288 threads, 4 elems each
    const float4 v = reinterpret_cast<const float4*>(in)[i];
    ushort4 o;
    o.x = f2bf(v.x); o.y = f2bf(v.y); o.z = f2bf(v.z); o.w = f2bf(v.w);
    reinterpret_cast<ushort4*>(out)[i] = o;
    if (i < BDIM) {
        minpos[i] = 0x7f800000;                      // +inf  (min over positives of sim+2)
        maxneg[i] = 0;                               // 0.0f  (max over negatives of sim+2)
    }
}

// ---- kernel 2: fused GEMM + masked row min/max ----
// block = 256 thr = 4 waves; wave w owns rows [bx*256 + w*64, +64) (ms=4).
// Block sweeps 512 cols (by), 32 at a time (nt=2); B-tile 32x256 bf16 = 16KB,
// double-buffered, staged with global_load_lds w16; swizzle chunk c of row r
// at position c^(r&7) applied on the GLOBAL source address.
__global__ __launch_bounds__(256, 2) void triplet_main(const u16* __restrict__ Ebf,
                                                       const int* __restrict__ labels,
                                                       int* __restrict__ minpos,
                                                       int* __restrict__ maxneg) {
    __shared__ __align__(16) u16 smem[2][32 * DDIM];  // 2 x 16 KB

    const int tid  = threadIdx.x;
    const int w    = tid >> 6;
    const int l    = tid & 63;
    const int quad = l >> 4;
    const int r16  = l & 15;

    const int mblk  = blockIdx.x * 256 + w * 64;     // wave's first row
    const int nbase = blockIdx.y * 512;

    // Preload A fragments: a[ms][k] covers rows [mblk+ms*16,+16), k-chunk [k*32,+32)
    bf16x8 a[4][8];
#pragma unroll
    for (int ms = 0; ms < 4; ++ms) {
        const u16* ap = Ebf + (size_t)(mblk + ms * 16 + r16) * DDIM + quad * 8;
#pragma unroll
        for (int k = 0; k < 8; ++k) a[ms][k] = ld_frag(ap + k * 32);
    }

    int lab_row[4][4];
#pragma unroll
    for (int ms = 0; ms < 4; ++ms)
#pragma unroll
        for (int r = 0; r < 4; ++r)
            lab_row[ms][r] = labels[mblk + ms * 16 + quad * 4 + r];

    float minp[4][4], maxn[4][4];
#pragma unroll
    for (int ms = 0; ms < 4; ++ms)
#pragma unroll
        for (int r = 0; r < 4; ++r) { minp[ms][r] = __builtin_inff(); maxn[ms][r] = -__builtin_inff(); }

    // swizzled-read lane constants
    const int qs = quad ^ (r16 & 3);                 // low-2-bit chunk index after swizzle
    const int s4 = (r16 >> 2) & 1;                   // bit-2 of swizzle

    // stage first tile (32 rows x 512B = 1024 chunks) into buf 0
#pragma unroll
    for (int it = 0; it < 4; ++it) {
        const int q = it * 256 + tid;
        const int r = q >> 5;
        const int c = (q & 31) ^ (r & 7);
        gload_lds16(Ebf + ((size_t)(nbase + r) << 8) + c * 8,
                    &smem[0][0] + it * 2048 + w * 512);
    }

    for (int nn = 0; nn < 16; ++nn) {
        const int cur = nn & 1;
        const int n0  = nbase + nn * 32;

        __syncthreads();   // staging of smem[cur] complete; smem[!cur] free

        if (nn + 1 < 16) {
            const int n1 = n0 + 32;
#pragma unroll
            for (int it = 0; it < 4; ++it) {
                const int q = it * 256 + tid;
                const int r = q >> 5;
                const int c = (q & 31) ^ (r & 7);
                gload_lds16(Ebf + ((size_t)(n1 + r) << 8) + c * 8,
                            &smem[cur ^ 1][0] + it * 2048 + w * 512);
            }
        }

        f32x4 acc[4][2];
#pragma unroll
        for (int ms = 0; ms < 4; ++ms)
#pragma unroll
            for (int nt = 0; nt < 2; ++nt)
                acc[ms][nt] = (f32x4){0.f, 0.f, 0.f, 0.f};

        const u16* bb = &smem[cur][0];
        const u16* bnt[2];
#pragma unroll
        for (int nt = 0; nt < 2; ++nt)
            bnt[nt] = bb + (nt * 16 + r16) * DDIM + qs * 8;

#pragma unroll
        for (int k = 0; k < 8; ++k) {
            const int koff = ((k ^ s4) << 5);
            bf16x8 b[2];
#pragma unroll
            for (int nt = 0; nt < 2; ++nt) b[nt] = ld_frag(bnt[nt] + koff);
#pragma unroll
            for (int ms = 0; ms < 4; ++ms)
#pragma unroll
                for (int nt = 0; nt < 2; ++nt)
                    acc[ms][nt] = __builtin_amdgcn_mfma_f32_16x16x32_bf16(
                        a[ms][k], b[nt], acc[ms][nt], 0, 0, 0);
        }

        // masked fold. Exact diag handling only where col range may hit row range.
        int lab_c[2];
#pragma unroll
        for (int nt = 0; nt < 2; ++nt) lab_c[nt] = labels[n0 + nt * 16 + r16];

        const bool diagTile = (n0 < mblk + 64) && (mblk < n0 + 32);
        if (__builtin_expect(diagTile, 0)) {
#pragma unroll
            for (int nt = 0; nt < 2; ++nt) {
                const int colg = n0 + nt * 16 + r16;
#pragma unroll
                for (int ms = 0; ms < 4; ++ms)
#pragma unroll
                    for (int r = 0; r < 4; ++r) {
                        const int rowg = mblk + ms * 16 + quad * 4 + r;
                        const float s = acc[ms][nt][r];
                        const bool same = (lab_c[nt] == lab_row[ms][r]);
                        const bool pos  = same && (colg != rowg);
                        minp[ms][r] = fminf(minp[ms][r], pos  ?  s : __builtin_inff());
                        maxn[ms][r] = fmaxf(maxn[ms][r], same ? -__builtin_inff() : s);
                    }
            }
        } else {
#pragma unroll
            for (int nt = 0; nt < 2; ++nt)
#pragma unroll
                for (int ms = 0; ms < 4; ++ms)
#pragma unroll
                    for (int r = 0; r < 4; ++r) {
                        const float s = acc[ms][nt][r];
                        const bool same = (lab_c[nt] == lab_row[ms][r]);
                        minp[ms][r] = fminf(minp[ms][r], same ?  s : __builtin_inff());
                        maxn[ms][r] = fmaxf(maxn[ms][r], same ? -__builtin_inff() : s);
                    }
        }
    }

    // reduce across the 16 lanes sharing a quad (same rows, different cols)
#pragma unroll
    for (int mask = 1; mask <= 8; mask <<= 1) {
#pragma unroll
        for (int ms = 0; ms < 4; ++ms)
#pragma unroll
            for (int r = 0; r < 4; ++r) {
                minp[ms][r] = fminf(minp[ms][r], __shfl_xor(minp[ms][r], mask, 64));
                maxn[ms][r] = fmaxf(maxn[ms][r], __shfl_xor(maxn[ms][r], mask, 64));
            }
    }
    if (r16 == 0) {
#pragma unroll
        for (int ms = 0; ms < 4; ++ms)
#pragma unroll
            for (int r = 0; r < 4; ++r) {
                const int rowg = mblk + ms * 16 + quad * 4 + r;
                atomicMin(minpos + rowg, __float_as_int(minp[ms][r] + 2.0f));
                atomicMax(maxneg + rowg, __float_as_int(maxn[ms][r] + 2.0f));
            }
    }
}

// ---- kernel 3: finalize (single block, 1024 threads) ----
__global__ __launch_bounds__(1024) void finalize_kernel(const int* __restrict__ minpos,
                                                        const int* __restrict__ maxneg,
                                                        float* __restrict__ out) {
    __shared__ float ssum[16], scnt[16];
    float sum = 0.f, cnt = 0.f;
#pragma unroll
    for (int it = 0; it < 8; ++it) {
        const int i = it * 1024 + threadIdx.x;
        const float mp = __int_as_float(minpos[i]);  // min(sim)+2 over positives; +inf if none
        const float mn = __int_as_float(maxneg[i]);  // max(sim)+2 over negatives; 0 if none
        if (mp < 1e30f && mn > 0.5f) {
            // dist = sqrt(2 - 2*sim), sim = stored - 2  =>  2 - 2*(stored-2) = 6 - 2*stored
            const float dap = sqrtf(fmaxf(6.0f - 2.0f * mp, 0.0f) + 1e-12f);
            const float dan = sqrtf(fmaxf(6.0f - 2.0f * mn, 0.0f) + 1e-12f);
            sum += fmaxf(dap - dan + 0.3f, 0.0f);
            cnt += 1.0f;
        }
    }
#pragma unroll
    for (int off = 32; off > 0; off >>= 1) {
        sum += __shfl_down(sum, off, 64);
        cnt += __shfl_down(cnt, off, 64);
    }
    const int wid = threadIdx.x >> 6;
    if ((threadIdx.x & 63) == 0) { ssum[wid] = sum; scnt[wid] = cnt; }
    __syncthreads();
    if (threadIdx.x == 0) {
        float S = 0.f, C = 0.f;
#pragma unroll
        for (int i = 0; i < 16; ++i) { S += ssum[i]; C += scnt[i]; }
        out[0] = (C > 0.f) ? (S / C) : 0.f;
    }
}

extern "C" void kernel_launch(void* const* d_in, const int* in_sizes, int n_in,
                              void* d_out, int out_size, void* d_ws, size_t ws_size,
                              hipStream_t stream) {
    const float* emb    = (const float*)d_in[0];
    const int*   labels = (const int*)d_in[1];
    float*       out    = (float*)d_out;

    u16* Ebf    = (u16*)d_ws;                                  // 4 MB
    int* minpos = (int*)((char*)d_ws + (size_t)BDIM * DDIM * 2);
    int* maxneg = minpos + BDIM;

    cvt_init_kernel<<<dim3((BDIM * DDIM / 4) / 256), dim3(256), 0, stream>>>(emb, Ebf, minpos, maxneg);
    triplet_main<<<dim3(BDIM / 256, BDIM / 512), dim3(256), 0, stream>>>(Ebf, labels, minpos, maxneg);
    finalize_kernel<<<dim3(1), dim3(1024), 0, stream>>>(minpos, maxneg, out);
}